// Round 5
// baseline (173.995 us; speedup 1.0000x reference)
//
#include <hip/hip_runtime.h>
#include <hip/hip_bf16.h>
#include <math.h>

// MemoryReader: B=16 H=8 M=64 K=32 R=65536 D_IN=512, OUT_DIM=520
// Outputs (FLOAT32, concatenated): flat_reads[16,512] | read_weights[16,8,32] |
//                                  read_indices[16,8,32] | read_strengths[16,8]

#define NB 16
#define NH 8
#define NM 64
#define NK 32
#define NR 65536
#define NDIN 512
#define NOUT 520
#define CHUNK 256
#define NCHUNK 256              // R / CHUNK
#define CAND 48                 // candidate slots per (chunk, head)
#define NCTOT (NCHUNK * CAND)   // 12288 candidates per (b,h)
#define FPT (NCTOT / 512)       // 24 per thread in k_final (512 threads)
#define STAGE1 (8 * CAND)       // 384 stage-1 survivors in k_final

#define OFF_READS 0
#define OFF_W 8192
#define OFF_I 12288
#define OFF_S 16384

// Direct global->LDS DMA, 16 B per lane. Dest must be WAVE-UNIFORM base;
// HW writes base + lane*16 (m97/m104). Source is per-lane (enables swizzle).
__device__ __forceinline__ void dma16(const void* g, void* l) {
  __builtin_amdgcn_global_load_lds(
      (const __attribute__((address_space(1))) unsigned int*)g,
      (__attribute__((address_space(3))) unsigned int*)l, 16, 0, 0);
}

__device__ __forceinline__ float dot4(float4 a, float4 b) {
  return a.x * b.x + a.y * b.y + a.z * b.z + a.w * b.w;
}

// Kernel 1: flat = x @ W^T + b; normalize keys per (b,h); emit strengths.
__global__ __launch_bounds__(512) void k_prep(
    const float* __restrict__ x, const float* __restrict__ W,
    const float* __restrict__ bias, float* __restrict__ sk_ws,
    float* __restrict__ str_ws, float* __restrict__ dout) {
  const int b = blockIdx.x, t = threadIdx.x;
  __shared__ float4 xs4[NDIN / 4];
  __shared__ float flat[NOUT];
  if (t < NDIN / 4) xs4[t] = reinterpret_cast<const float4*>(x + (size_t)b * NDIN)[t];
  __syncthreads();
  {
    const float4* Wr = reinterpret_cast<const float4*>(W + (size_t)t * NDIN);
    float acc = 0.f;
    for (int i = 0; i < NDIN / 4; ++i) acc += dot4(Wr[i], xs4[i]);
    flat[t] = acc + bias[t];
  }
  if (t < NOUT - NDIN) {
    const int j = NDIN + t;
    const float4* Wr = reinterpret_cast<const float4*>(W + (size_t)j * NDIN);
    float acc = 0.f;
    for (int i = 0; i < NDIN / 4; ++i) acc += dot4(Wr[i], xs4[i]);
    flat[j] = acc + bias[j];
  }
  __syncthreads();
  // t = h*64 + m; each 64-lane wave is exactly one head h.
  float v = flat[t];
  float ss = v * v;
  #pragma unroll
  for (int off = 32; off >= 1; off >>= 1) ss += __shfl_xor(ss, off, 64);
  float rn = 1.0f / fmaxf(sqrtf(ss), 1e-12f);
  sk_ws[(size_t)b * NDIN + t] = v * rn;
  if (t < NH) {
    float s = flat[NDIN + t];
    str_ws[b * NH + t] = s;
    dout[OFF_S + b * NH + t] = s;
  }
}

// Kernel 2: per (b, 256-row chunk): DMA-stage rows to LDS (coalesced 1-KiB
// transactions, source-side XOR swizzle), per-thread-row scores for 8 heads
// (sk4 reads are wave-uniform broadcasts), then per-wave shfl-only candidate
// selection. 2 blocks/CU (79 KB LDS) pipelines DMA across blocks.
__global__ __launch_bounds__(256) void k_score(
    const float* __restrict__ mem, const float* __restrict__ sk_ws,
    const float* __restrict__ str_ws, float* __restrict__ cv_ws,
    unsigned* __restrict__ ci_ws) {
  const int b = blockIdx.x >> 8;
  const int chunk = blockIdx.x & 255;
  const int base = chunk * CHUNK;
  const int t = threadIdx.x;
  const int lane = t & 63, w = t >> 6;  // 4 waves

  __shared__ float4 stage[4][64][16];   // 64 KB: per-wave 64 rows x 256 B
  __shared__ float4 sk4[NH * NM / 4];   // 2 KB
  __shared__ float str[NH];
  __shared__ float sc[NH][CHUNK + 1];   // pad: conflict-free selection reads
  __shared__ float candv[NH][CAND];
  __shared__ unsigned candi[NH][CAND];
  __shared__ unsigned cnt_s[NH];

  // ---- issue DMA first (latency overlaps sk4 setup + barrier) ----
  // LDS slot (rL, s) receives global seg (s ^ (rL&15)) of row rL: the read
  // side XORs the same way, so ds_read banks spread 8/bank (vs 64-way linear).
  {
    const size_t rowbase = (size_t)b * NR + base + w * 64;
    #pragma unroll
    for (int i = 0; i < 16; ++i) {
      const int rL = 4 * i + (lane >> 4);
      const int seg = (lane & 15) ^ (rL & 15);
      dma16(mem + (rowbase + rL) * NM + seg * 4, &stage[w][4 * i][0]);
    }
  }
  if (t < 128) sk4[t] = reinterpret_cast<const float4*>(sk_ws + (size_t)b * NDIN)[t];
  if (t < NH) str[t] = str_ws[b * NH + t];
  asm volatile("s_waitcnt vmcnt(0)" ::: "memory");
  __syncthreads();

  // ---- score phase: one LDS row per thread ----
  {
    const int z = lane & 15;
    const float4* myrow = &stage[w][lane][0];
    float acc[NH];
    #pragma unroll
    for (int h = 0; h < NH; ++h) acc[h] = 0.f;
    float ss = 0.f;
    #pragma unroll
    for (int i = 0; i < 16; ++i) {
      float4 va = myrow[i ^ z];          // = global seg i of this row
      ss += dot4(va, va);
      #pragma unroll
      for (int h = 0; h < NH; ++h) acc[h] += dot4(va, sk4[h * 16 + i]);
    }
    float rn = 1.0f / fmaxf(sqrtf(ss), 1e-12f);
    #pragma unroll
    for (int h = 0; h < NH; ++h) sc[h][w * 64 + lane] = str[h] * (acc[h] * rn);
  }
  __syncthreads();  // the only selection-relevant block barrier

  // ---- selection: wave w handles heads w and w+4, fully wave-private ----
  for (int hh = 0; hh < 2; ++hh) {
    const int h = w + hh * 4;
    float v[4];
    #pragma unroll
    for (int j = 0; j < 4; ++j) v[j] = sc[h][lane + 64 * j];

    float mx = v[0], mn = v[0];
    #pragma unroll
    for (int j = 1; j < 4; ++j) { mx = fmaxf(mx, v[j]); mn = fminf(mn, v[j]); }
    #pragma unroll
    for (int off = 32; off >= 1; off >>= 1) {
      mx = fmaxf(mx, __shfl_xor(mx, off, 64));
      mn = fminf(mn, __shfl_xor(mn, off, 64));
    }

    // binary search for T with count(>T) in [NK, CAND] — shfl-only
    float lo = mn - 1.0f, hi = mx, T = lo;
    bool found = false;
    for (int it = 0; it < 48; ++it) {
      float mid = 0.5f * (lo + hi);
      if (!(mid > lo && mid < hi)) break;
      unsigned c = 0;
      #pragma unroll
      for (int j = 0; j < 4; ++j) c += (v[j] > mid) ? 1u : 0u;
      #pragma unroll
      for (int off = 32; off >= 1; off >>= 1) c += __shfl_xor(c, off, 64);
      if (c >= NK) {
        lo = mid;
        if (c <= CAND) { T = mid; found = true; break; }
      } else {
        hi = mid;
      }
    }
    if (!found) T = lo;  // invariant: count(>lo) >= NK

    if (lane == 0) cnt_s[h] = 0u;
    // same-wave LDS ordering: write above precedes the atomics below
    #pragma unroll
    for (int j = 0; j < 4; ++j) {
      if (v[j] > T) {
        unsigned p = atomicAdd(&cnt_s[h], 1u);
        if (p < CAND) { candv[h][p] = v[j]; candi[h][p] = (unsigned)(base + lane + 64 * j); }
      }
    }
    unsigned c = cnt_s[h];
    for (unsigned p = c + (unsigned)lane; p < CAND; p += 64u) {
      candv[h][p] = -INFINITY; candi[h][p] = 0x7F000000u + p;
    }
    if (lane < CAND) {
      size_t o = (((size_t)(b * NH + h)) * NCHUNK + chunk) * CAND + lane;
      cv_ws[o] = candv[h][lane];
      ci_ws[o] = candi[h][lane];
    }
  }
}

// Kernel 3: per (b,h): stage-1 per-wave top-[32,48] supersets (shfl-only) over
// 12288 candidates, stage-2 rank-based exact sorted top-32 over <=384, then
// softmax + gather.
__global__ __launch_bounds__(512) void k_final(
    const float* __restrict__ mem, const float* __restrict__ cv_ws,
    const unsigned* __restrict__ ci_ws, float* __restrict__ dout) {
  const int bh = blockIdx.x;
  const int b = bh >> 3;
  const int t = threadIdx.x;
  const int lane = t & 63, w = t >> 6;  // 8 waves

  __shared__ float cv[STAGE1];
  __shared__ unsigned ci[STAGE1];
  __shared__ unsigned cnt_s[8];
  __shared__ float fv[NK];
  __shared__ unsigned fi[NK];
  __shared__ float wts[NK];
  __shared__ unsigned widx[NK];

  const float* CV = cv_ws + (size_t)bh * NCTOT;
  const unsigned* CI = ci_ws + (size_t)bh * NCTOT;

  float v[FPT];
  unsigned vi[FPT];
  #pragma unroll
  for (int i = 0; i < FPT; ++i) {
    v[i] = CV[i * 512 + t];
    vi[i] = CI[i * 512 + t];
  }

  // wave-local range (exclude -INF pads from min)
  float mx = -INFINITY, mn = INFINITY;
  #pragma unroll
  for (int i = 0; i < FPT; ++i) {
    mx = fmaxf(mx, v[i]);
    if (v[i] > -1e37f) mn = fminf(mn, v[i]);
  }
  #pragma unroll
  for (int off = 32; off >= 1; off >>= 1) {
    mx = fmaxf(mx, __shfl_xor(mx, off, 64));
    mn = fminf(mn, __shfl_xor(mn, off, 64));
  }

  // wave-local binary search: count(>T) in [NK, CAND] over this wave's 1536
  float lo = mn - 1.0f, hi = mx, T = lo;
  bool found = false;
  for (int it = 0; it < 48; ++it) {
    float mid = 0.5f * (lo + hi);
    if (!(mid > lo && mid < hi)) break;
    unsigned c = 0;
    #pragma unroll
    for (int i = 0; i < FPT; ++i) c += (v[i] > mid) ? 1u : 0u;
    #pragma unroll
    for (int off = 32; off >= 1; off >>= 1) c += __shfl_xor(c, off, 64);
    if (c >= NK) {
      lo = mid;
      if (c <= CAND) { T = mid; found = true; break; }
    } else {
      hi = mid;
    }
  }
  if (!found) T = lo;

  if (lane == 0) cnt_s[w] = 0u;
  #pragma unroll
  for (int i = 0; i < FPT; ++i) {
    if (v[i] > T) {
      unsigned p = atomicAdd(&cnt_s[w], 1u);
      if (p < CAND) { cv[w * CAND + p] = v[i]; ci[w * CAND + p] = vi[i]; }
    }
  }
  {
    unsigned c = cnt_s[w];
    for (unsigned p = c + (unsigned)lane; p < CAND; p += 64u) {
      cv[w * CAND + p] = -INFINITY;
      ci[w * CAND + p] = 0x7F100000u + w * CAND + p;
    }
  }
  __syncthreads();

  // stage 2: exact rank (val desc, idx asc); top-32 land sorted in fv/fi
  if (t < STAGE1) {
    float myv = cv[t];
    unsigned myi = ci[t];
    int rank = 0;
    for (int j = 0; j < STAGE1; ++j) {
      float vj = cv[j];
      unsigned ij = ci[j];
      rank += ((vj > myv) || (vj == myv && ij < myi)) ? 1 : 0;
    }
    if (rank < NK) { fv[rank] = myv; fi[rank] = myi; }
  }
  __syncthreads();

  // softmax over the sorted top-32 (fv[0] is the max)
  if (t < NK) {
    float e = expf(fv[t] - fv[0]);
    float s = e;
    #pragma unroll
    for (int off = 16; off >= 1; off >>= 1) s += __shfl_xor(s, off, 32);
    float wgt = e / s;
    wts[t] = wgt;
    widx[t] = fi[t];
    dout[OFF_W + bh * NK + t] = wgt;
    dout[OFF_I + bh * NK + t] = (float)fi[t];
  }
  __syncthreads();

  // memory_reads[b,h,m] = sum_k w_k * mem[b, idx_k, m]
  if (t < NM) {
    float acc = 0.f;
    #pragma unroll 8
    for (int k = 0; k < NK; ++k) {
      unsigned gi = widx[k] < NR ? widx[k] : 0u;  // defensive clamp
      acc += wts[k] * mem[((size_t)b * NR + gi) * NM + t];
    }
    dout[OFF_READS + bh * NM + t] = acc;
  }
}

extern "C" void kernel_launch(void* const* d_in, const int* in_sizes, int n_in,
                              void* d_out, int out_size, void* d_ws, size_t ws_size,
                              hipStream_t stream) {
  const float* x    = (const float*)d_in[0];  // read_inputs (16,512)
  const float* mem  = (const float*)d_in[1];  // mem_state (16,65536,64)
  const float* W    = (const float*)d_in[2];  // (520,512)
  const float* bias = (const float*)d_in[3];  // (520,)
  float* out = (float*)d_out;

  char* ws = (char*)d_ws;
  float* sk_ws    = (float*)ws;                   // 32 KB
  float* str_ws   = (float*)(ws + 32768);         // 512 B
  const size_t cand_bytes = (size_t)NB * NH * NCTOT * 4;  // 6.3 MB
  float* cv_ws    = (float*)(ws + 65536);
  unsigned* ci_ws = (unsigned*)(ws + 65536 + cand_bytes);

  hipLaunchKernelGGL(k_prep, dim3(NB), dim3(512), 0, stream, x, W, bias, sk_ws, str_ws, out);
  hipLaunchKernelGGL(k_score, dim3(NB * NCHUNK), dim3(256), 0, stream, mem, sk_ws, str_ws, cv_ws, ci_ws);
  hipLaunchKernelGGL(k_final, dim3(NB * NH), dim3(512), 0, stream, mem, cv_ws, ci_ws, out);
}

// Round 6
// 96.212 us; speedup vs baseline: 1.8085x; 1.8085x over previous
//
#include <hip/hip_runtime.h>
#include <hip/hip_bf16.h>
#include <math.h>

// MemoryReader: B=16 H=8 M=64 K=32 R=65536 D_IN=512, OUT_DIM=520
// Outputs (FLOAT32, concatenated): flat_reads[16,512] | read_weights[16,8,32] |
//                                  read_indices[16,8,32] | read_strengths[16,8]

#define NB 16
#define NH 8
#define NM 64
#define NK 32
#define NR 65536
#define NDIN 512
#define NOUT 520
#define CHUNK 512
#define NCHUNK 128      // R / CHUNK
#define CAND 48         // candidate slots per (chunk, head); count target in [NK, CAND]
#define NCTOT (NCHUNK * CAND)   // 6144 candidates per (b,h)
#define FPT (NCTOT / 256)       // 24 per thread in k_final
#define STAGE1 (4 * CAND)       // 192 stage-1 survivors in k_final
#define SCP 516                 // sc stride: 4h+g banks all distinct -> conflict-free

#define OFF_READS 0
#define OFF_W 8192
#define OFF_I 12288
#define OFF_S 16384

__device__ __forceinline__ float dot4(float4 a, float4 b) {
  return a.x * b.x + a.y * b.y + a.z * b.z + a.w * b.w;
}

// Kernel 1: flat = x @ W^T + b, split over (b, head) blocks so W reads spread
// across 144 CUs (was: 16 blocks x 1 MB of W each = 20-40 us on 16 CUs).
__global__ __launch_bounds__(256) void k_prep(
    const float* __restrict__ x, const float* __restrict__ W,
    const float* __restrict__ bias, float* __restrict__ sk_ws,
    float* __restrict__ str_ws, float* __restrict__ dout) {
  const int blk = blockIdx.x;          // 0..143
  const int b = blk / 9, h = blk % 9;  // h==8: strengths block
  const int t = threadIdx.x;           // 256 threads
  __shared__ float4 xs4[NDIN / 4];
  __shared__ float flat64[NM];
  if (t < 128) xs4[t] = reinterpret_cast<const float4*>(x + (size_t)b * NDIN)[t];
  __syncthreads();
  if (h < 8) {
    // 64 outputs, 4 threads each over 128 contiguous floats
    const int j = h * 64 + (t >> 2);
    const int p = t & 3;
    const float4* Wr = reinterpret_cast<const float4*>(W + (size_t)j * NDIN);
    float acc = 0.f;
    #pragma unroll 8
    for (int i = p * 32; i < p * 32 + 32; ++i) acc += dot4(Wr[i], xs4[i]);
    acc += __shfl_xor(acc, 1, 64);
    acc += __shfl_xor(acc, 2, 64);
    if (p == 0) flat64[t >> 2] = acc + bias[j];
    __syncthreads();
    if (t < 64) {  // wave 0: normalize this head's 64 keys
      float v = flat64[t];
      float ss = v * v;
      #pragma unroll
      for (int off = 32; off >= 1; off >>= 1) ss += __shfl_xor(ss, off, 64);
      float rn = 1.0f / fmaxf(sqrtf(ss), 1e-12f);
      sk_ws[(size_t)b * NDIN + h * 64 + t] = v * rn;
    }
  } else {
    // 8 strength outputs, 32 threads each
    const int j = NDIN + (t >> 5);
    const int p = t & 31;
    const float4* Wr = reinterpret_cast<const float4*>(W + (size_t)j * NDIN);
    float acc = 0.f;
    #pragma unroll
    for (int i = p * 4; i < p * 4 + 4; ++i) acc += dot4(Wr[i], xs4[i]);
    #pragma unroll
    for (int off = 16; off >= 1; off >>= 1) acc += __shfl_xor(acc, off, 64);
    if (p == 0) {
      float s = acc + bias[j];
      str_ws[b * NH + (t >> 5)] = s;
      dout[OFF_S + b * NH + (t >> 5)] = s;
    }
  }
}

// Kernel 2: per (b, 512-row chunk). Wave w owns rows [w*64, w*64+64):
// fully-coalesced loads (lane = consecutive float4 -> 16 sectors/instr, 4x
// less TA work than row-per-thread), per-16-lane-group halving-exchange
// shuffle reduce routes head hl=bitrev3(lane&7) to each lane, one
// conflict-free ds_write per iteration. Selection = R4 (shfl-only).
__global__ __launch_bounds__(512, 6) void k_score(
    const float* __restrict__ mem, const float* __restrict__ sk_ws,
    const float* __restrict__ str_ws, float* __restrict__ cv_ws,
    unsigned* __restrict__ ci_ws) {
  const int b = blockIdx.x >> 7;
  const int chunk = blockIdx.x & 127;
  const int base = chunk * CHUNK;
  const int t = threadIdx.x;
  const int lane = t & 63, w = t >> 6;  // 8 waves

  __shared__ float sc_f[NH * SCP];      // 16.5 KB, stride 516
  __shared__ float4 sk4[NH * 16];       // 2 KB
  __shared__ float str_s[NH];
  __shared__ float candv[NH][CAND];
  __shared__ unsigned candi[NH][CAND];
  __shared__ unsigned cnt_s[NH];

  if (t < 128) sk4[t] = reinterpret_cast<const float4*>(sk_ws + (size_t)b * NDIN)[t];
  if (t < NH) str_s[t] = str_ws[b * NH + t];
  __syncthreads();

  // per-lane preload: seg s of all 8 heads' keys (32 VGPR), + this lane's head
  const int s = lane & 15;
  const float4 k0 = sk4[0 * 16 + s], k1 = sk4[1 * 16 + s];
  const float4 k2 = sk4[2 * 16 + s], k3 = sk4[3 * 16 + s];
  const float4 k4 = sk4[4 * 16 + s], k5 = sk4[5 * 16 + s];
  const float4 k6 = sk4[6 * 16 + s], k7 = sk4[7 * 16 + s];
  const int hl = ((lane & 1) << 2) | (lane & 2) | ((lane >> 2) & 1);
  const float str_l = str_s[hl];
  const int g = lane >> 4;
  float* myslot = &sc_f[hl * SCP + w * 64 + g];

  const float4* mem4 =
      reinterpret_cast<const float4*>(mem + ((size_t)b * NR + base + w * 64) * NM);

  // ---- score phase: iteration i covers rows 4i..4i+3 of this wave ----
  #pragma unroll 2
  for (int i = 0; i < 16; ++i) {
    float4 va = mem4[i * 64 + lane];  // coalesced 1 KB per wave instr
    float ss = dot4(va, va);
    float a0 = dot4(va, k0), a1 = dot4(va, k1), a2 = dot4(va, k2), a3 = dot4(va, k3);
    float a4 = dot4(va, k4), a5 = dot4(va, k5), a6 = dot4(va, k6), a7 = dot4(va, k7);
    // row-norm: full butterfly over the 16-lane group
    ss += __shfl_xor(ss, 1, 64); ss += __shfl_xor(ss, 2, 64);
    ss += __shfl_xor(ss, 4, 64); ss += __shfl_xor(ss, 8, 64);
    // halving exchange: head bit2 <- lane bit0
    {
      const bool bit = (lane & 1) != 0;
      float s0 = bit ? a0 : a4, p0 = bit ? a4 : a0;
      float s1 = bit ? a1 : a5, p1 = bit ? a5 : a1;
      float s2 = bit ? a2 : a6, p2 = bit ? a6 : a2;
      float s3 = bit ? a3 : a7, p3 = bit ? a7 : a3;
      a0 = p0 + __shfl_xor(s0, 1, 64);
      a1 = p1 + __shfl_xor(s1, 1, 64);
      a2 = p2 + __shfl_xor(s2, 1, 64);
      a3 = p3 + __shfl_xor(s3, 1, 64);
    }
    // head bit1 <- lane bit1
    {
      const bool bit = (lane & 2) != 0;
      float s0 = bit ? a0 : a2, p0 = bit ? a2 : a0;
      float s1 = bit ? a1 : a3, p1 = bit ? a3 : a1;
      a0 = p0 + __shfl_xor(s0, 2, 64);
      a1 = p1 + __shfl_xor(s1, 2, 64);
    }
    // head bit0 <- lane bit2
    {
      const bool bit = (lane & 4) != 0;
      float s0 = bit ? a0 : a1, p0 = bit ? a1 : a0;
      a0 = p0 + __shfl_xor(s0, 4, 64);
    }
    a0 += __shfl_xor(a0, 8, 64);  // combine the two 8-lane halves
    float rn = 1.0f / fmaxf(sqrtf(ss), 1e-12f);
    // lanes l and l^8 hold identical (row,head): same-addr write, 2-way = free
    myslot[4 * i] = str_l * (a0 * rn);
  }
  __syncthreads();  // the only selection-relevant block barrier

  // ---- selection: wave w handles head w, fully wave-private ----
  {
    const int h = w;
    float v[8];
    #pragma unroll
    for (int j = 0; j < 8; ++j) v[j] = sc_f[h * SCP + lane + 64 * j];

    float mx = v[0], mn = v[0];
    #pragma unroll
    for (int j = 1; j < 8; ++j) { mx = fmaxf(mx, v[j]); mn = fminf(mn, v[j]); }
    #pragma unroll
    for (int off = 32; off >= 1; off >>= 1) {
      mx = fmaxf(mx, __shfl_xor(mx, off, 64));
      mn = fminf(mn, __shfl_xor(mn, off, 64));
    }

    // binary search for T with count(>T) in [NK, CAND] — shfl-only
    float lo = mn - 1.0f, hi = mx, T = lo;
    bool found = false;
    for (int it = 0; it < 48; ++it) {
      float mid = 0.5f * (lo + hi);
      if (!(mid > lo && mid < hi)) break;
      unsigned c = 0;
      #pragma unroll
      for (int j = 0; j < 8; ++j) c += (v[j] > mid) ? 1u : 0u;
      #pragma unroll
      for (int off = 32; off >= 1; off >>= 1) c += __shfl_xor(c, off, 64);
      if (c >= NK) {
        lo = mid;
        if (c <= CAND) { T = mid; found = true; break; }
      } else {
        hi = mid;
      }
    }
    if (!found) T = lo;  // invariant: count(>lo) >= NK

    if (lane == 0) cnt_s[h] = 0u;
    // same-wave LDS ordering: write above precedes the atomics below
    #pragma unroll
    for (int j = 0; j < 8; ++j) {
      if (v[j] > T) {
        unsigned p = atomicAdd(&cnt_s[h], 1u);
        if (p < CAND) { candv[h][p] = v[j]; candi[h][p] = (unsigned)(base + lane + 64 * j); }
      }
    }
    unsigned c = cnt_s[h];
    for (unsigned p = c + (unsigned)lane; p < CAND; p += 64u) {
      candv[h][p] = -INFINITY; candi[h][p] = 0x7F000000u + p;
    }
    if (lane < CAND) {
      size_t o = (((size_t)(b * NH + h)) * NCHUNK + chunk) * CAND + lane;
      cv_ws[o] = candv[h][lane];
      ci_ws[o] = candi[h][lane];
    }
  }
}

// Kernel 3: per (b,h): stage-1 per-wave top-[32,48] supersets (shfl-only),
// stage-2 rank-based exact sorted top-32 over <=192 survivors, then softmax +
// gather. (R4-identical, known-good.)
__global__ __launch_bounds__(256) void k_final(
    const float* __restrict__ mem, const float* __restrict__ cv_ws,
    const unsigned* __restrict__ ci_ws, float* __restrict__ dout) {
  const int bh = blockIdx.x;
  const int b = bh >> 3;
  const int t = threadIdx.x;
  const int lane = t & 63, w = t >> 6;  // 4 waves

  __shared__ float cv[STAGE1];
  __shared__ unsigned ci[STAGE1];
  __shared__ unsigned cnt_s[4];
  __shared__ float fv[NK];
  __shared__ unsigned fi[NK];
  __shared__ float wts[NK];
  __shared__ unsigned widx[NK];

  const float* CV = cv_ws + (size_t)bh * NCTOT;
  const unsigned* CI = ci_ws + (size_t)bh * NCTOT;

  float v[FPT];
  unsigned vi[FPT];
  #pragma unroll
  for (int i = 0; i < FPT; ++i) {
    v[i] = CV[i * 256 + t];
    vi[i] = CI[i * 256 + t];
  }

  // wave-local range (exclude -INF pads from min)
  float mx = -INFINITY, mn = INFINITY;
  #pragma unroll
  for (int i = 0; i < FPT; ++i) {
    mx = fmaxf(mx, v[i]);
    if (v[i] > -1e37f) mn = fminf(mn, v[i]);
  }
  #pragma unroll
  for (int off = 32; off >= 1; off >>= 1) {
    mx = fmaxf(mx, __shfl_xor(mx, off, 64));
    mn = fminf(mn, __shfl_xor(mn, off, 64));
  }

  // wave-local binary search: count(>T) in [NK, CAND] over this wave's 1536
  float lo = mn - 1.0f, hi = mx, T = lo;
  bool found = false;
  for (int it = 0; it < 48; ++it) {
    float mid = 0.5f * (lo + hi);
    if (!(mid > lo && mid < hi)) break;
    unsigned c = 0;
    #pragma unroll
    for (int i = 0; i < FPT; ++i) c += (v[i] > mid) ? 1u : 0u;
    #pragma unroll
    for (int off = 32; off >= 1; off >>= 1) c += __shfl_xor(c, off, 64);
    if (c >= NK) {
      lo = mid;
      if (c <= CAND) { T = mid; found = true; break; }
    } else {
      hi = mid;
    }
  }
  if (!found) T = lo;

  if (lane == 0) cnt_s[w] = 0u;
  #pragma unroll
  for (int i = 0; i < FPT; ++i) {
    if (v[i] > T) {
      unsigned p = atomicAdd(&cnt_s[w], 1u);
      if (p < CAND) { cv[w * CAND + p] = v[i]; ci[w * CAND + p] = vi[i]; }
    }
  }
  {
    unsigned c = cnt_s[w];
    for (unsigned p = c + (unsigned)lane; p < CAND; p += 64u) {
      cv[w * CAND + p] = -INFINITY;
      ci[w * CAND + p] = 0x7F100000u + w * CAND + p;
    }
  }
  __syncthreads();

  // stage 2: exact rank (val desc, idx asc); top-32 land sorted in fv/fi
  if (t < STAGE1) {
    float myv = cv[t];
    unsigned myi = ci[t];
    int rank = 0;
    for (int j = 0; j < STAGE1; ++j) {
      float vj = cv[j];
      unsigned ij = ci[j];
      rank += ((vj > myv) || (vj == myv && ij < myi)) ? 1 : 0;
    }
    if (rank < NK) { fv[rank] = myv; fi[rank] = myi; }
  }
  __syncthreads();

  // softmax over the sorted top-32 (fv[0] is the max)
  if (t < NK) {
    float e = expf(fv[t] - fv[0]);
    float sum = e;
    #pragma unroll
    for (int off = 16; off >= 1; off >>= 1) sum += __shfl_xor(sum, off, 32);
    float wgt = e / sum;
    wts[t] = wgt;
    widx[t] = fi[t];
    dout[OFF_W + bh * NK + t] = wgt;
    dout[OFF_I + bh * NK + t] = (float)fi[t];
  }
  __syncthreads();

  // memory_reads[b,h,m] = sum_k w_k * mem[b, idx_k, m]
  if (t < NM) {
    float acc = 0.f;
    #pragma unroll 8
    for (int k = 0; k < NK; ++k) {
      unsigned gi = widx[k] < NR ? widx[k] : 0u;  // defensive clamp
      acc += wts[k] * mem[((size_t)b * NR + gi) * NM + t];
    }
    dout[OFF_READS + bh * NM + t] = acc;
  }
}

extern "C" void kernel_launch(void* const* d_in, const int* in_sizes, int n_in,
                              void* d_out, int out_size, void* d_ws, size_t ws_size,
                              hipStream_t stream) {
  const float* x    = (const float*)d_in[0];  // read_inputs (16,512)
  const float* mem  = (const float*)d_in[1];  // mem_state (16,65536,64)
  const float* W    = (const float*)d_in[2];  // (520,512)
  const float* bias = (const float*)d_in[3];  // (520,)
  float* out = (float*)d_out;

  char* ws = (char*)d_ws;
  float* sk_ws    = (float*)ws;                   // 32 KB
  float* str_ws   = (float*)(ws + 32768);         // 512 B
  const size_t cand_bytes = (size_t)NB * NH * NCTOT * 4;  // 3.15 MB
  float* cv_ws    = (float*)(ws + 65536);
  unsigned* ci_ws = (unsigned*)(ws + 65536 + cand_bytes);

  hipLaunchKernelGGL(k_prep, dim3(NB * 9), dim3(256), 0, stream, x, W, bias, sk_ws, str_ws, out);
  hipLaunchKernelGGL(k_score, dim3(NB * NCHUNK), dim3(512), 0, stream, mem, sk_ws, str_ws, cv_ws, ci_ws);
  hipLaunchKernelGGL(k_final, dim3(NB * NH), dim3(256), 0, stream, mem, cv_ws, ci_ws, out);
}

// Round 7
// 95.868 us; speedup vs baseline: 1.8149x; 1.0036x over previous
//
#include <hip/hip_runtime.h>
#include <hip/hip_bf16.h>
#include <math.h>

// MemoryReader: B=16 H=8 M=64 K=32 R=65536 D_IN=512, OUT_DIM=520
// Outputs (FLOAT32, concatenated): flat_reads[16,512] | read_weights[16,8,32] |
//                                  read_indices[16,8,32] | read_strengths[16,8]

#define NB 16
#define NH 8
#define NM 64
#define NK 32
#define NR 65536
#define NDIN 512
#define NOUT 520
#define CHUNK 512
#define NCHUNK 128      // R / CHUNK
#define CAND 48         // candidate slots per (chunk, head); count target in [NK, CAND]
#define NCTOT (NCHUNK * CAND)   // 6144 candidates per (b,h)
#define FPT (NCTOT / 256)       // 24 per thread in k_final
#define STAGE1 (4 * CAND)       // 192 stage-1 survivors in k_final
#define SCP 516                 // sc stride: 4h+g banks all distinct -> conflict-free

#define OFF_READS 0
#define OFF_W 8192
#define OFF_I 12288
#define OFF_S 16384

__device__ __forceinline__ float dot4(float4 a, float4 b) {
  return a.x * b.x + a.y * b.y + a.z * b.z + a.w * b.w;
}

// Kernel 1: flat = x @ W^T + b, split over (b, head) blocks so W reads spread
// across 144 CUs.
__global__ __launch_bounds__(256) void k_prep(
    const float* __restrict__ x, const float* __restrict__ W,
    const float* __restrict__ bias, float* __restrict__ sk_ws,
    float* __restrict__ str_ws, float* __restrict__ dout) {
  const int blk = blockIdx.x;          // 0..143
  const int b = blk / 9, h = blk % 9;  // h==8: strengths block
  const int t = threadIdx.x;           // 256 threads
  __shared__ float4 xs4[NDIN / 4];
  __shared__ float flat64[NM];
  if (t < 128) xs4[t] = reinterpret_cast<const float4*>(x + (size_t)b * NDIN)[t];
  __syncthreads();
  if (h < 8) {
    // 64 outputs, 4 threads each over 128 contiguous floats
    const int j = h * 64 + (t >> 2);
    const int p = t & 3;
    const float4* Wr = reinterpret_cast<const float4*>(W + (size_t)j * NDIN);
    float acc = 0.f;
    #pragma unroll 8
    for (int i = p * 32; i < p * 32 + 32; ++i) acc += dot4(Wr[i], xs4[i]);
    acc += __shfl_xor(acc, 1, 64);
    acc += __shfl_xor(acc, 2, 64);
    if (p == 0) flat64[t >> 2] = acc + bias[j];
    __syncthreads();
    if (t < 64) {  // wave 0: normalize this head's 64 keys
      float v = flat64[t];
      float ss = v * v;
      #pragma unroll
      for (int off = 32; off >= 1; off >>= 1) ss += __shfl_xor(ss, off, 64);
      float rn = 1.0f / fmaxf(sqrtf(ss), 1e-12f);
      sk_ws[(size_t)b * NDIN + h * 64 + t] = v * rn;
    }
  } else {
    // 8 strength outputs, 32 threads each
    const int j = NDIN + (t >> 5);
    const int p = t & 31;
    const float4* Wr = reinterpret_cast<const float4*>(W + (size_t)j * NDIN);
    float acc = 0.f;
    #pragma unroll
    for (int i = p * 4; i < p * 4 + 4; ++i) acc += dot4(Wr[i], xs4[i]);
    #pragma unroll
    for (int off = 16; off >= 1; off >>= 1) acc += __shfl_xor(acc, off, 64);
    if (p == 0) {
      float s = acc + bias[j];
      str_ws[b * NH + (t >> 5)] = s;
      dout[OFF_S + b * NH + (t >> 5)] = s;
    }
  }
}

// Kernel 2: per (b, 512-row chunk). Wave w owns rows [w*64, w*64+64):
// fully-coalesced float4 loads, 4-BATCHED per iteration for memory-level
// parallelism (the per-row shuffle-reduce chain is ~8 shfl deep; batching
// decouples load issue from it). Per-16-lane-group halving-exchange routes
// head hl=bitrev3(lane&7) to each lane; one conflict-free ds_write per row
// quartet. Selection: per-wave shfl-only binary search (R4/R6 known-good).
__global__ __launch_bounds__(512, 6) void k_score(
    const float* __restrict__ mem, const float* __restrict__ sk_ws,
    const float* __restrict__ str_ws, float* __restrict__ cv_ws,
    unsigned* __restrict__ ci_ws) {
  const int b = blockIdx.x >> 7;
  const int chunk = blockIdx.x & 127;
  const int base = chunk * CHUNK;
  const int t = threadIdx.x;
  const int lane = t & 63, w = t >> 6;  // 8 waves

  __shared__ float sc_f[NH * SCP];      // 16.5 KB, stride 516
  __shared__ float4 sk4[NH * 16];       // 2 KB
  __shared__ float str_s[NH];
  __shared__ float candv[NH][CAND];
  __shared__ unsigned candi[NH][CAND];
  __shared__ unsigned cnt_s[NH];

  if (t < 128) sk4[t] = reinterpret_cast<const float4*>(sk_ws + (size_t)b * NDIN)[t];
  if (t < NH) str_s[t] = str_ws[b * NH + t];
  __syncthreads();

  // per-lane preload: seg s of all 8 heads' keys (32 VGPR), + this lane's head
  const int s = lane & 15;
  const float4 k0 = sk4[0 * 16 + s], k1 = sk4[1 * 16 + s];
  const float4 k2 = sk4[2 * 16 + s], k3 = sk4[3 * 16 + s];
  const float4 k4 = sk4[4 * 16 + s], k5 = sk4[5 * 16 + s];
  const float4 k6 = sk4[6 * 16 + s], k7 = sk4[7 * 16 + s];
  const int hl = ((lane & 1) << 2) | (lane & 2) | ((lane >> 2) & 1);
  const float str_l = str_s[hl];
  const int g = lane >> 4;
  float* myslot = &sc_f[hl * SCP + w * 64 + g];

  const float4* mem4 =
      reinterpret_cast<const float4*>(mem + ((size_t)b * NR + base + w * 64) * NM);

  // one row-quartet's full reduce chain
  auto process = [&](float4 va, int i) {
    float ss = dot4(va, va);
    float a0 = dot4(va, k0), a1 = dot4(va, k1), a2 = dot4(va, k2), a3 = dot4(va, k3);
    float a4 = dot4(va, k4), a5 = dot4(va, k5), a6 = dot4(va, k6), a7 = dot4(va, k7);
    // row-norm: full butterfly over the 16-lane group
    ss += __shfl_xor(ss, 1, 64); ss += __shfl_xor(ss, 2, 64);
    ss += __shfl_xor(ss, 4, 64); ss += __shfl_xor(ss, 8, 64);
    // halving exchange: head bit2 <- lane bit0
    {
      const bool bit = (lane & 1) != 0;
      float s0 = bit ? a0 : a4, p0 = bit ? a4 : a0;
      float s1 = bit ? a1 : a5, p1 = bit ? a5 : a1;
      float s2 = bit ? a2 : a6, p2 = bit ? a6 : a2;
      float s3 = bit ? a3 : a7, p3 = bit ? a7 : a3;
      a0 = p0 + __shfl_xor(s0, 1, 64);
      a1 = p1 + __shfl_xor(s1, 1, 64);
      a2 = p2 + __shfl_xor(s2, 1, 64);
      a3 = p3 + __shfl_xor(s3, 1, 64);
    }
    // head bit1 <- lane bit1
    {
      const bool bit = (lane & 2) != 0;
      float s0 = bit ? a0 : a2, p0 = bit ? a2 : a0;
      float s1 = bit ? a1 : a3, p1 = bit ? a3 : a1;
      a0 = p0 + __shfl_xor(s0, 2, 64);
      a1 = p1 + __shfl_xor(s1, 2, 64);
    }
    // head bit0 <- lane bit2
    {
      const bool bit = (lane & 4) != 0;
      float s0 = bit ? a0 : a1, p0 = bit ? a1 : a0;
      a0 = p0 + __shfl_xor(s0, 4, 64);
    }
    a0 += __shfl_xor(a0, 8, 64);  // combine the two 8-lane halves
    float rn = 1.0f / fmaxf(sqrtf(ss), 1e-12f);
    // lanes l and l^8 hold identical (row,head): same-addr write, 2-way = free
    myslot[4 * i] = str_l * (a0 * rn);
  };

  // ---- score phase: 4 batched independent loads per step ----
  #pragma unroll
  for (int ib = 0; ib < 4; ++ib) {
    float4 va0 = mem4[(4 * ib + 0) * 64 + lane];
    float4 va1 = mem4[(4 * ib + 1) * 64 + lane];
    float4 va2 = mem4[(4 * ib + 2) * 64 + lane];
    float4 va3 = mem4[(4 * ib + 3) * 64 + lane];
    process(va0, 4 * ib + 0);
    process(va1, 4 * ib + 1);
    process(va2, 4 * ib + 2);
    process(va3, 4 * ib + 3);
  }
  __syncthreads();  // the only selection-relevant block barrier

  // ---- selection: wave w handles head w, fully wave-private ----
  {
    const int h = w;
    float v[8];
    #pragma unroll
    for (int j = 0; j < 8; ++j) v[j] = sc_f[h * SCP + lane + 64 * j];

    float mx = v[0], mn = v[0];
    #pragma unroll
    for (int j = 1; j < 8; ++j) { mx = fmaxf(mx, v[j]); mn = fminf(mn, v[j]); }
    #pragma unroll
    for (int off = 32; off >= 1; off >>= 1) {
      mx = fmaxf(mx, __shfl_xor(mx, off, 64));
      mn = fminf(mn, __shfl_xor(mn, off, 64));
    }

    // binary search for T with count(>T) in [NK, CAND] — shfl-only
    float lo = mn - 1.0f, hi = mx, T = lo;
    bool found = false;
    for (int it = 0; it < 48; ++it) {
      float mid = 0.5f * (lo + hi);
      if (!(mid > lo && mid < hi)) break;
      unsigned c = 0;
      #pragma unroll
      for (int j = 0; j < 8; ++j) c += (v[j] > mid) ? 1u : 0u;
      #pragma unroll
      for (int off = 32; off >= 1; off >>= 1) c += __shfl_xor(c, off, 64);
      if (c >= NK) {
        lo = mid;
        if (c <= CAND) { T = mid; found = true; break; }
      } else {
        hi = mid;
      }
    }
    if (!found) T = lo;  // invariant: count(>lo) >= NK

    if (lane == 0) cnt_s[h] = 0u;
    // same-wave LDS ordering: write above precedes the atomics below
    #pragma unroll
    for (int j = 0; j < 8; ++j) {
      if (v[j] > T) {
        unsigned p = atomicAdd(&cnt_s[h], 1u);
        if (p < CAND) { candv[h][p] = v[j]; candi[h][p] = (unsigned)(base + lane + 64 * j); }
      }
    }
    unsigned c = cnt_s[h];
    for (unsigned p = c + (unsigned)lane; p < CAND; p += 64u) {
      candv[h][p] = -INFINITY; candi[h][p] = 0x7F000000u + p;
    }
    if (lane < CAND) {
      size_t o = (((size_t)(b * NH + h)) * NCHUNK + chunk) * CAND + lane;
      cv_ws[o] = candv[h][lane];
      ci_ws[o] = candi[h][lane];
    }
  }
}

// Kernel 3: per (b,h): stage-1 per-wave top-[32,48] supersets (shfl-only),
// stage-2 rank-based exact sorted top-32 over <=192 survivors, then softmax +
// gather. (known-good since R4)
__global__ __launch_bounds__(256) void k_final(
    const float* __restrict__ mem, const float* __restrict__ cv_ws,
    const unsigned* __restrict__ ci_ws, float* __restrict__ dout) {
  const int bh = blockIdx.x;
  const int b = bh >> 3;
  const int t = threadIdx.x;
  const int lane = t & 63, w = t >> 6;  // 4 waves

  __shared__ float cv[STAGE1];
  __shared__ unsigned ci[STAGE1];
  __shared__ unsigned cnt_s[4];
  __shared__ float fv[NK];
  __shared__ unsigned fi[NK];
  __shared__ float wts[NK];
  __shared__ unsigned widx[NK];

  const float* CV = cv_ws + (size_t)bh * NCTOT;
  const unsigned* CI = ci_ws + (size_t)bh * NCTOT;

  float v[FPT];
  unsigned vi[FPT];
  #pragma unroll
  for (int i = 0; i < FPT; ++i) {
    v[i] = CV[i * 256 + t];
    vi[i] = CI[i * 256 + t];
  }

  // wave-local range (exclude -INF pads from min)
  float mx = -INFINITY, mn = INFINITY;
  #pragma unroll
  for (int i = 0; i < FPT; ++i) {
    mx = fmaxf(mx, v[i]);
    if (v[i] > -1e37f) mn = fminf(mn, v[i]);
  }
  #pragma unroll
  for (int off = 32; off >= 1; off >>= 1) {
    mx = fmaxf(mx, __shfl_xor(mx, off, 64));
    mn = fminf(mn, __shfl_xor(mn, off, 64));
  }

  // wave-local binary search: count(>T) in [NK, CAND] over this wave's 1536
  float lo = mn - 1.0f, hi = mx, T = lo;
  bool found = false;
  for (int it = 0; it < 48; ++it) {
    float mid = 0.5f * (lo + hi);
    if (!(mid > lo && mid < hi)) break;
    unsigned c = 0;
    #pragma unroll
    for (int i = 0; i < FPT; ++i) c += (v[i] > mid) ? 1u : 0u;
    #pragma unroll
    for (int off = 32; off >= 1; off >>= 1) c += __shfl_xor(c, off, 64);
    if (c >= NK) {
      lo = mid;
      if (c <= CAND) { T = mid; found = true; break; }
    } else {
      hi = mid;
    }
  }
  if (!found) T = lo;

  if (lane == 0) cnt_s[w] = 0u;
  #pragma unroll
  for (int i = 0; i < FPT; ++i) {
    if (v[i] > T) {
      unsigned p = atomicAdd(&cnt_s[w], 1u);
      if (p < CAND) { cv[w * CAND + p] = v[i]; ci[w * CAND + p] = vi[i]; }
    }
  }
  {
    unsigned c = cnt_s[w];
    for (unsigned p = c + (unsigned)lane; p < CAND; p += 64u) {
      cv[w * CAND + p] = -INFINITY;
      ci[w * CAND + p] = 0x7F100000u + w * CAND + p;
    }
  }
  __syncthreads();

  // stage 2: exact rank (val desc, idx asc); top-32 land sorted in fv/fi
  if (t < STAGE1) {
    float myv = cv[t];
    unsigned myi = ci[t];
    int rank = 0;
    for (int j = 0; j < STAGE1; ++j) {
      float vj = cv[j];
      unsigned ij = ci[j];
      rank += ((vj > myv) || (vj == myv && ij < myi)) ? 1 : 0;
    }
    if (rank < NK) { fv[rank] = myv; fi[rank] = myi; }
  }
  __syncthreads();

  // softmax over the sorted top-32 (fv[0] is the max)
  if (t < NK) {
    float e = expf(fv[t] - fv[0]);
    float sum = e;
    #pragma unroll
    for (int off = 16; off >= 1; off >>= 1) sum += __shfl_xor(sum, off, 32);
    float wgt = e / sum;
    wts[t] = wgt;
    widx[t] = fi[t];
    dout[OFF_W + bh * NK + t] = wgt;
    dout[OFF_I + bh * NK + t] = (float)fi[t];
  }
  __syncthreads();

  // memory_reads[b,h,m] = sum_k w_k * mem[b, idx_k, m]
  if (t < NM) {
    float acc = 0.f;
    #pragma unroll 8
    for (int k = 0; k < NK; ++k) {
      unsigned gi = widx[k] < NR ? widx[k] : 0u;  // defensive clamp
      acc += wts[k] * mem[((size_t)b * NR + gi) * NM + t];
    }
    dout[OFF_READS + bh * NM + t] = acc;
  }
}

extern "C" void kernel_launch(void* const* d_in, const int* in_sizes, int n_in,
                              void* d_out, int out_size, void* d_ws, size_t ws_size,
                              hipStream_t stream) {
  const float* x    = (const float*)d_in[0];  // read_inputs (16,512)
  const float* mem  = (const float*)d_in[1];  // mem_state (16,65536,64)
  const float* W    = (const float*)d_in[2];  // (520,512)
  const float* bias = (const float*)d_in[3];  // (520,)
  float* out = (float*)d_out;

  char* ws = (char*)d_ws;
  float* sk_ws    = (float*)ws;                   // 32 KB
  float* str_ws   = (float*)(ws + 32768);         // 512 B
  const size_t cand_bytes = (size_t)NB * NH * NCTOT * 4;  // 3.15 MB
  float* cv_ws    = (float*)(ws + 65536);
  unsigned* ci_ws = (unsigned*)(ws + 65536 + cand_bytes);

  hipLaunchKernelGGL(k_prep, dim3(NB * 9), dim3(256), 0, stream, x, W, bias, sk_ws, str_ws, out);
  hipLaunchKernelGGL(k_score, dim3(NB * NCHUNK), dim3(512), 0, stream, mem, sk_ws, str_ws, cv_ws, ci_ws);
  hipLaunchKernelGGL(k_final, dim3(NB * NH), dim3(256), 0, stream, mem, cv_ws, ci_ws, out);
}

// Round 8
// 79.609 us; speedup vs baseline: 2.1856x; 1.2042x over previous
//
#include <hip/hip_runtime.h>
#include <hip/hip_bf16.h>
#include <math.h>

// MemoryReader: B=16 H=8 M=64 K=32 R=65536 D_IN=512, OUT_DIM=520
// Outputs (FLOAT32, concatenated): flat_reads[16,512] | read_weights[16,8,32] |
//                                  read_indices[16,8,32] | read_strengths[16,8]

#define NB 16
#define NH 8
#define NM 64
#define NK 32
#define NR 65536
#define NDIN 512
#define NOUT 520
#define CHUNK 512
#define NCHUNK 128      // R / CHUNK
#define CAND 48         // candidate slots per (chunk, head); count target in [NK, CAND]
#define NCTOT (NCHUNK * CAND)   // 6144 candidates per (b,h)
#define FPT (NCTOT / 256)       // 24 per thread in k_final
#define STAGE1 (4 * CAND)       // 192 stage-1 survivors in k_final
#define SCP 516                 // sc stride: 4h+g banks all distinct -> conflict-free

#define OFF_READS 0
#define OFF_W 8192
#define OFF_I 12288
#define OFF_S 16384

__device__ __forceinline__ float dot4(float4 a, float4 b) {
  return a.x * b.x + a.y * b.y + a.z * b.z + a.w * b.w;
}

// ---- DPP cross-lane helpers (VALU pipe, zero DS-pipe traffic) ----
// quad_perm 0xB1 = [1,0,3,2] (xor-1), 0x4E = [2,3,0,1] (xor-2),
// 0x104/0x114 = row_shl:4 / row_shr:4 (lane i <- i+4 / i-4 within row16),
// 0x124/0x128 = row_ror:4 / row_ror:8 (ror8 == exact xor-8 within row16).
template <int CTRL>
__device__ __forceinline__ float dppf(float x) {
  return __int_as_float(__builtin_amdgcn_update_dpp(
      0, __float_as_int(x), CTRL, 0xF, 0xF, true));
}
template <int CTRL>
__device__ __forceinline__ int dppi(int x) {
  return __builtin_amdgcn_update_dpp(0, x, CTRL, 0xF, 0xF, true);
}
__device__ __forceinline__ float rdlf(float x, int l) {
  return __int_as_float(__builtin_amdgcn_readlane(__float_as_int(x), l));
}
// 64-lane reductions -> wave-uniform scalar (DPP within row16, readlane across)
__device__ __forceinline__ float wmax64(float x) {
  x = fmaxf(x, dppf<0xB1>(x));
  x = fmaxf(x, dppf<0x4E>(x));
  x = fmaxf(x, dppf<0x124>(x));
  x = fmaxf(x, dppf<0x128>(x));
  return fmaxf(fmaxf(rdlf(x, 0), rdlf(x, 16)), fmaxf(rdlf(x, 32), rdlf(x, 48)));
}
__device__ __forceinline__ float wmin64(float x) {
  x = fminf(x, dppf<0xB1>(x));
  x = fminf(x, dppf<0x4E>(x));
  x = fminf(x, dppf<0x124>(x));
  x = fminf(x, dppf<0x128>(x));
  return fminf(fminf(rdlf(x, 0), rdlf(x, 16)), fminf(rdlf(x, 32), rdlf(x, 48)));
}
__device__ __forceinline__ unsigned wsum64u(unsigned c) {
  int x = (int)c;
  x += dppi<0xB1>(x);
  x += dppi<0x4E>(x);
  x += dppi<0x124>(x);
  x += dppi<0x128>(x);
  return (unsigned)(__builtin_amdgcn_readlane(x, 0) + __builtin_amdgcn_readlane(x, 16) +
                    __builtin_amdgcn_readlane(x, 32) + __builtin_amdgcn_readlane(x, 48));
}

// Kernel 1: flat = x @ W^T + b, split over (b, head) blocks so W reads spread
// across 144 CUs.
__global__ __launch_bounds__(256) void k_prep(
    const float* __restrict__ x, const float* __restrict__ W,
    const float* __restrict__ bias, float* __restrict__ sk_ws,
    float* __restrict__ str_ws, float* __restrict__ dout) {
  const int blk = blockIdx.x;          // 0..143
  const int b = blk / 9, h = blk % 9;  // h==8: strengths block
  const int t = threadIdx.x;           // 256 threads
  __shared__ float4 xs4[NDIN / 4];
  __shared__ float flat64[NM];
  if (t < 128) xs4[t] = reinterpret_cast<const float4*>(x + (size_t)b * NDIN)[t];
  __syncthreads();
  if (h < 8) {
    const int j = h * 64 + (t >> 2);
    const int p = t & 3;
    const float4* Wr = reinterpret_cast<const float4*>(W + (size_t)j * NDIN);
    float acc = 0.f;
    #pragma unroll 8
    for (int i = p * 32; i < p * 32 + 32; ++i) acc += dot4(Wr[i], xs4[i]);
    acc += __shfl_xor(acc, 1, 64);
    acc += __shfl_xor(acc, 2, 64);
    if (p == 0) flat64[t >> 2] = acc + bias[j];
    __syncthreads();
    if (t < 64) {  // wave 0: normalize this head's 64 keys
      float v = flat64[t];
      float ss = v * v;
      #pragma unroll
      for (int off = 32; off >= 1; off >>= 1) ss += __shfl_xor(ss, off, 64);
      float rn = 1.0f / fmaxf(sqrtf(ss), 1e-12f);
      sk_ws[(size_t)b * NDIN + h * 64 + t] = v * rn;
    }
  } else {
    const int j = NDIN + (t >> 5);
    const int p = t & 31;
    const float4* Wr = reinterpret_cast<const float4*>(W + (size_t)j * NDIN);
    float acc = 0.f;
    #pragma unroll
    for (int i = p * 4; i < p * 4 + 4; ++i) acc += dot4(Wr[i], xs4[i]);
    #pragma unroll
    for (int off = 16; off >= 1; off >>= 1) acc += __shfl_xor(acc, off, 64);
    if (p == 0) {
      float s = acc + bias[j];
      str_ws[b * NH + (t >> 5)] = s;
      dout[OFF_S + b * NH + (t >> 5)] = s;
    }
  }
}

// Kernel 2: per (b, 512-row chunk). Coalesced float4 loads (4-batched); the
// per-row reduce/transpose tree runs ENTIRELY on DPP (VALU) — the old
// __shfl_xor version put ~18 ds_bpermute ops per KiB on the per-CU DS pipe,
// saturating it at HBM pace. Now: 1 ds_write per KiB. Selection binary search
// also DPP+readlane (uniform, 0 DS).
__global__ __launch_bounds__(512, 6) void k_score(
    const float* __restrict__ mem, const float* __restrict__ sk_ws,
    const float* __restrict__ str_ws, float* __restrict__ cv_ws,
    unsigned* __restrict__ ci_ws) {
  const int b = blockIdx.x >> 7;
  const int chunk = blockIdx.x & 127;
  const int base = chunk * CHUNK;
  const int t = threadIdx.x;
  const int lane = t & 63, w = t >> 6;  // 8 waves

  __shared__ float sc_f[NH * SCP];      // 16.5 KB, stride 516
  __shared__ float4 sk4[NH * 16];       // 2 KB
  __shared__ float str_s[NH];
  __shared__ float candv[NH][CAND];
  __shared__ unsigned candi[NH][CAND];
  __shared__ unsigned cnt_s[NH];

  if (t < 128) sk4[t] = reinterpret_cast<const float4*>(sk_ws + (size_t)b * NDIN)[t];
  if (t < NH) str_s[t] = str_ws[b * NH + t];
  __syncthreads();

  // per-lane preload: seg s of all 8 heads' keys (32 VGPR), + this lane's head
  const int s = lane & 15;
  const float4 k0 = sk4[0 * 16 + s], k1 = sk4[1 * 16 + s];
  const float4 k2 = sk4[2 * 16 + s], k3 = sk4[3 * 16 + s];
  const float4 k4 = sk4[4 * 16 + s], k5 = sk4[5 * 16 + s];
  const float4 k6 = sk4[6 * 16 + s], k7 = sk4[7 * 16 + s];
  const int hl = ((lane & 1) << 2) | (lane & 2) | ((lane >> 2) & 1);
  const float str_l = str_s[hl];
  const int g = lane >> 4;
  float* myslot = &sc_f[hl * SCP + w * 64 + g];

  const float4* mem4 =
      reinterpret_cast<const float4*>(mem + ((size_t)b * NR + base + w * 64) * NM);

  // one row-quartet's full reduce chain — all cross-lane via DPP (VALU pipe)
  auto process = [&](float4 va, int i) {
    float ss = dot4(va, va);
    float a0 = dot4(va, k0), a1 = dot4(va, k1), a2 = dot4(va, k2), a3 = dot4(va, k3);
    float a4 = dot4(va, k4), a5 = dot4(va, k5), a6 = dot4(va, k6), a7 = dot4(va, k7);
    // row-norm: rotate-reduce sum over the 16-lane group
    ss += dppf<0xB1>(ss);
    ss += dppf<0x4E>(ss);
    ss += dppf<0x124>(ss);
    ss += dppf<0x128>(ss);
    // halving exchange stage 1: head bit2 <- lane bit0 (exact xor-1)
    {
      const bool bit = (lane & 1) != 0;
      float s0 = bit ? a0 : a4, p0 = bit ? a4 : a0;
      float s1 = bit ? a1 : a5, p1 = bit ? a5 : a1;
      float s2 = bit ? a2 : a6, p2 = bit ? a6 : a2;
      float s3 = bit ? a3 : a7, p3 = bit ? a7 : a3;
      a0 = p0 + dppf<0xB1>(s0);
      a1 = p1 + dppf<0xB1>(s1);
      a2 = p2 + dppf<0xB1>(s2);
      a3 = p3 + dppf<0xB1>(s3);
    }
    // stage 2: head bit1 <- lane bit1 (exact xor-2)
    {
      const bool bit = (lane & 2) != 0;
      float s0 = bit ? a0 : a2, p0 = bit ? a2 : a0;
      float s1 = bit ? a1 : a3, p1 = bit ? a3 : a1;
      a0 = p0 + dppf<0x4E>(s0);
      a1 = p1 + dppf<0x4E>(s1);
    }
    // stage 3: head bit0 <- lane bit2 (exact xor-4 via shl/shr + select)
    {
      const bool bit = (lane & 4) != 0;
      float s0 = bit ? a0 : a1, p0 = bit ? a1 : a0;
      float xlo = dppf<0x104>(s0);  // row_shl:4 — lane i <- i+4
      float xhi = dppf<0x114>(s0);  // row_shr:4 — lane i <- i-4
      a0 = p0 + (bit ? xhi : xlo);
    }
    a0 += dppf<0x128>(a0);  // combine halves: row_ror:8 == exact xor-8 in row16
    float rn = 1.0f / fmaxf(sqrtf(ss), 1e-12f);
    // lanes l and l^8 hold identical (row,head): same-addr write, 2-way = free
    myslot[4 * i] = str_l * (a0 * rn);
  };

  // ---- score phase: 4 batched independent loads per step ----
  #pragma unroll
  for (int ib = 0; ib < 4; ++ib) {
    float4 va0 = mem4[(4 * ib + 0) * 64 + lane];
    float4 va1 = mem4[(4 * ib + 1) * 64 + lane];
    float4 va2 = mem4[(4 * ib + 2) * 64 + lane];
    float4 va3 = mem4[(4 * ib + 3) * 64 + lane];
    process(va0, 4 * ib + 0);
    process(va1, 4 * ib + 1);
    process(va2, 4 * ib + 2);
    process(va3, 4 * ib + 3);
  }
  __syncthreads();  // the only selection-relevant block barrier

  // ---- selection: wave w handles head w, fully wave-private ----
  {
    const int h = w;
    float v[8];
    #pragma unroll
    for (int j = 0; j < 8; ++j) v[j] = sc_f[h * SCP + lane + 64 * j];

    float mxl = v[0], mnl = v[0];
    #pragma unroll
    for (int j = 1; j < 8; ++j) { mxl = fmaxf(mxl, v[j]); mnl = fminf(mnl, v[j]); }
    float mx = wmax64(mxl);
    float mn = wmin64(mnl);

    // binary search for T with count(>T) in [NK, CAND] — DPP+readlane, 0 DS
    float lo = mn - 1.0f, hi = mx, T = lo;
    bool found = false;
    for (int it = 0; it < 48; ++it) {
      float mid = 0.5f * (lo + hi);
      if (!(mid > lo && mid < hi)) break;
      unsigned c = 0;
      #pragma unroll
      for (int j = 0; j < 8; ++j) c += (v[j] > mid) ? 1u : 0u;
      c = wsum64u(c);
      if (c >= NK) {
        lo = mid;
        if (c <= CAND) { T = mid; found = true; break; }
      } else {
        hi = mid;
      }
    }
    if (!found) T = lo;  // invariant: count(>lo) >= NK

    if (lane == 0) cnt_s[h] = 0u;
    // same-wave LDS ordering: write above precedes the atomics below
    #pragma unroll
    for (int j = 0; j < 8; ++j) {
      if (v[j] > T) {
        unsigned p = atomicAdd(&cnt_s[h], 1u);
        if (p < CAND) { candv[h][p] = v[j]; candi[h][p] = (unsigned)(base + lane + 64 * j); }
      }
    }
    unsigned c = cnt_s[h];
    for (unsigned p = c + (unsigned)lane; p < CAND; p += 64u) {
      candv[h][p] = -INFINITY; candi[h][p] = 0x7F000000u + p;
    }
    if (lane < CAND) {
      size_t o = (((size_t)(b * NH + h)) * NCHUNK + chunk) * CAND + lane;
      cv_ws[o] = candv[h][lane];
      ci_ws[o] = candi[h][lane];
    }
  }
}

// Kernel 3: per (b,h): stage-1 per-wave top-[32,48] supersets (shfl-only),
// stage-2 rank-based exact sorted top-32 over <=192 survivors, then softmax +
// gather. (known-good since R4)
__global__ __launch_bounds__(256) void k_final(
    const float* __restrict__ mem, const float* __restrict__ cv_ws,
    const unsigned* __restrict__ ci_ws, float* __restrict__ dout) {
  const int bh = blockIdx.x;
  const int b = bh >> 3;
  const int t = threadIdx.x;
  const int lane = t & 63, w = t >> 6;  // 4 waves

  __shared__ float cv[STAGE1];
  __shared__ unsigned ci[STAGE1];
  __shared__ unsigned cnt_s[4];
  __shared__ float fv[NK];
  __shared__ unsigned fi[NK];
  __shared__ float wts[NK];
  __shared__ unsigned widx[NK];

  const float* CV = cv_ws + (size_t)bh * NCTOT;
  const unsigned* CI = ci_ws + (size_t)bh * NCTOT;

  float v[FPT];
  unsigned vi[FPT];
  #pragma unroll
  for (int i = 0; i < FPT; ++i) {
    v[i] = CV[i * 256 + t];
    vi[i] = CI[i * 256 + t];
  }

  // wave-local range (exclude -INF pads from min)
  float mx = -INFINITY, mn = INFINITY;
  #pragma unroll
  for (int i = 0; i < FPT; ++i) {
    mx = fmaxf(mx, v[i]);
    if (v[i] > -1e37f) mn = fminf(mn, v[i]);
  }
  #pragma unroll
  for (int off = 32; off >= 1; off >>= 1) {
    mx = fmaxf(mx, __shfl_xor(mx, off, 64));
    mn = fminf(mn, __shfl_xor(mn, off, 64));
  }

  // wave-local binary search: count(>T) in [NK, CAND] over this wave's 1536
  float lo = mn - 1.0f, hi = mx, T = lo;
  bool found = false;
  for (int it = 0; it < 48; ++it) {
    float mid = 0.5f * (lo + hi);
    if (!(mid > lo && mid < hi)) break;
    unsigned c = 0;
    #pragma unroll
    for (int i = 0; i < FPT; ++i) c += (v[i] > mid) ? 1u : 0u;
    #pragma unroll
    for (int off = 32; off >= 1; off >>= 1) c += __shfl_xor(c, off, 64);
    if (c >= NK) {
      lo = mid;
      if (c <= CAND) { T = mid; found = true; break; }
    } else {
      hi = mid;
    }
  }
  if (!found) T = lo;

  if (lane == 0) cnt_s[w] = 0u;
  #pragma unroll
  for (int i = 0; i < FPT; ++i) {
    if (v[i] > T) {
      unsigned p = atomicAdd(&cnt_s[w], 1u);
      if (p < CAND) { cv[w * CAND + p] = v[i]; ci[w * CAND + p] = vi[i]; }
    }
  }
  {
    unsigned c = cnt_s[w];
    for (unsigned p = c + (unsigned)lane; p < CAND; p += 64u) {
      cv[w * CAND + p] = -INFINITY;
      ci[w * CAND + p] = 0x7F100000u + w * CAND + p;
    }
  }
  __syncthreads();

  // stage 2: exact rank (val desc, idx asc); top-32 land sorted in fv/fi
  if (t < STAGE1) {
    float myv = cv[t];
    unsigned myi = ci[t];
    int rank = 0;
    for (int j = 0; j < STAGE1; ++j) {
      float vj = cv[j];
      unsigned ij = ci[j];
      rank += ((vj > myv) || (vj == myv && ij < myi)) ? 1 : 0;
    }
    if (rank < NK) { fv[rank] = myv; fi[rank] = myi; }
  }
  __syncthreads();

  // softmax over the sorted top-32 (fv[0] is the max)
  if (t < NK) {
    float e = expf(fv[t] - fv[0]);
    float sum = e;
    #pragma unroll
    for (int off = 16; off >= 1; off >>= 1) sum += __shfl_xor(sum, off, 32);
    float wgt = e / sum;
    wts[t] = wgt;
    widx[t] = fi[t];
    dout[OFF_W + bh * NK + t] = wgt;
    dout[OFF_I + bh * NK + t] = (float)fi[t];
  }
  __syncthreads();

  // memory_reads[b,h,m] = sum_k w_k * mem[b, idx_k, m]
  if (t < NM) {
    float acc = 0.f;
    #pragma unroll 8
    for (int k = 0; k < NK; ++k) {
      unsigned gi = widx[k] < NR ? widx[k] : 0u;  // defensive clamp
      acc += wts[k] * mem[((size_t)b * NR + gi) * NM + t];
    }
    dout[OFF_READS + bh * NM + t] = acc;
  }
}

extern "C" void kernel_launch(void* const* d_in, const int* in_sizes, int n_in,
                              void* d_out, int out_size, void* d_ws, size_t ws_size,
                              hipStream_t stream) {
  const float* x    = (const float*)d_in[0];  // read_inputs (16,512)
  const float* mem  = (const float*)d_in[1];  // mem_state (16,65536,64)
  const float* W    = (const float*)d_in[2];  // (520,512)
  const float* bias = (const float*)d_in[3];  // (520,)
  float* out = (float*)d_out;

  char* ws = (char*)d_ws;
  float* sk_ws    = (float*)ws;                   // 32 KB
  float* str_ws   = (float*)(ws + 32768);         // 512 B
  const size_t cand_bytes = (size_t)NB * NH * NCTOT * 4;  // 3.15 MB
  float* cv_ws    = (float*)(ws + 65536);
  unsigned* ci_ws = (unsigned*)(ws + 65536 + cand_bytes);

  hipLaunchKernelGGL(k_prep, dim3(NB * 9), dim3(256), 0, stream, x, W, bias, sk_ws, str_ws, out);
  hipLaunchKernelGGL(k_score, dim3(NB * NCHUNK), dim3(512), 0, stream, mem, sk_ws, str_ws, cv_ws, ci_ws);
  hipLaunchKernelGGL(k_final, dim3(NB * NH), dim3(256), 0, stream, mem, cv_ws, ci_ws, out);
}